// Round 1
// baseline (310.228 us; speedup 1.0000x reference)
//
#include <hip/hip_runtime.h>
#include <hip/hip_bf16.h>

#define LL 4096
#define DD 512
#define BB 8
#define KSEL 41

typedef __attribute__((ext_vector_type(4))) float f32x4;
typedef __attribute__((ext_vector_type(8))) short short8;

__device__ __forceinline__ ushort f2bf(float x) {
  __hip_bfloat16 h = __float2bfloat16(x);
  return *reinterpret_cast<ushort*>(&h);
}

__device__ __forceinline__ void g2lds16(const void* g, void* l) {
  __builtin_amdgcn_global_load_lds(
      (const __attribute__((address_space(1))) unsigned int*)g,
      (__attribute__((address_space(3))) unsigned int*)l, 16, 0, 0);
}

// ---------------- K1a: partial column sums of q,k over L ----------------
__global__ __launch_bounds__(128) void k_colsum(const float* __restrict__ q,
                                                const float* __restrict__ kk,
                                                float* __restrict__ qpart,
                                                float* __restrict__ kpart) {
  int lc = blockIdx.x, b = blockIdx.y;
  int c4 = threadIdx.x * 4;
  float aq0 = 0, aq1 = 0, aq2 = 0, aq3 = 0, ak0 = 0, ak1 = 0, ak2 = 0, ak3 = 0;
  const float* qp = q + ((size_t)b * LL + (size_t)lc * 64) * DD + c4;
  const float* kp = kk + ((size_t)b * LL + (size_t)lc * 64) * DD + c4;
#pragma unroll 4
  for (int l = 0; l < 64; ++l) {
    float4 x = *(const float4*)(qp + (size_t)l * DD);
    float4 y = *(const float4*)(kp + (size_t)l * DD);
    aq0 += x.x; aq1 += x.y; aq2 += x.z; aq3 += x.w;
    ak0 += y.x; ak1 += y.y; ak2 += y.z; ak3 += y.w;
  }
  float4 oq = {aq0, aq1, aq2, aq3};
  float4 ok = {ak0, ak1, ak2, ak3};
  *(float4*)&qpart[((size_t)b * 64 + lc) * DD + c4] = oq;
  *(float4*)&kpart[((size_t)b * 64 + lc) * DD + c4] = ok;
}

// ---------------- K1b: reduce partials -> sq, sk [B][D] ----------------
__global__ __launch_bounds__(128) void k_colsum2(const float* __restrict__ qpart,
                                                 const float* __restrict__ kpart,
                                                 float* __restrict__ sq,
                                                 float* __restrict__ sk) {
  int b = blockIdx.x;
  int c4 = threadIdx.x * 4;
  float aq0 = 0, aq1 = 0, aq2 = 0, aq3 = 0, ak0 = 0, ak1 = 0, ak2 = 0, ak3 = 0;
  for (int p = 0; p < 64; ++p) {
    float4 x = *(const float4*)&qpart[((size_t)b * 64 + p) * DD + c4];
    float4 y = *(const float4*)&kpart[((size_t)b * 64 + p) * DD + c4];
    aq0 += x.x; aq1 += x.y; aq2 += x.z; aq3 += x.w;
    ak0 += y.x; ak1 += y.y; ak2 += y.z; ak3 += y.w;
  }
  float4 oq = {aq0, aq1, aq2, aq3};
  float4 ok = {ak0, ak1, ak2, ak3};
  *(float4*)&sq[(size_t)b * DD + c4] = oq;
  *(float4*)&sk[(size_t)b * DD + c4] = ok;
}

// ------- K2: Sq/Sk via Wq/Wk, mean_value, top-41, softmax weights, bvo -------
__global__ __launch_bounds__(512) void k_stats(
    const float* __restrict__ sq, const float* __restrict__ sk,
    const float* __restrict__ Wq, const float* __restrict__ bq,
    const float* __restrict__ Wk, const float* __restrict__ bk,
    const float* __restrict__ bv, const float* __restrict__ Wo,
    const float* __restrict__ bo,
    int* __restrict__ idx_out, float* __restrict__ wts_out,
    float* __restrict__ bvo_out) {
  __shared__ float sqs[BB][DD];
  __shared__ float sks[BB][DD];
  __shared__ float mvs[BB][64];
  __shared__ float mab[64];
  __shared__ int idxs[64];
  int tid = threadIdx.x;
  for (int b = 0; b < BB; ++b) {
    sqs[b][tid] = sq[b * DD + tid];
    sks[b][tid] = sk[b * DD + tid];
  }
  __syncthreads();
  float aq[BB], ak[BB];
#pragma unroll
  for (int b = 0; b < BB; ++b) { aq[b] = 0.f; ak[b] = 0.f; }
  for (int j = 0; j < DD; ++j) {
    float wq = Wq[(size_t)j * DD + tid];
    float wk = Wk[(size_t)j * DD + tid];
#pragma unroll
    for (int b = 0; b < BB; ++b) { aq[b] += sqs[b][j] * wq; ak[b] += sks[b][j] * wk; }
  }
  float bqv = bq[tid] * (float)LL, bkv = bk[tid] * (float)LL;
  __syncthreads();
  for (int b = 0; b < BB; ++b) {
    sqs[b][tid] = aq[b] + bqv;   // now holds Sq
    sks[b][tid] = ak[b] + bkv;   // now holds Sk
  }
  __syncthreads();
  {
    int b = tid >> 6, d = tid & 63;
    float s = 0.f;
#pragma unroll
    for (int h = 0; h < 8; ++h) s += sqs[b][h * 64 + d] * sks[b][h * 64 + d];
    mvs[b][d] = s * (1.0f / ((float)LL * 8.0f));
  }
  __syncthreads();
  if (tid < 64) {
    float s = 0.f;
#pragma unroll
    for (int b = 0; b < BB; ++b) s += mvs[b][tid];
    mab[tid] = s * 0.125f;
  }
  __syncthreads();
  if (tid < 64) {
    float x = mab[tid];
    int r = 0;
    for (int d = 0; d < 64; ++d) {
      float y = mab[d];
      r += (y > x || (y == x && d < tid)) ? 1 : 0;
    }
    if (r < KSEL) { idxs[r] = tid; idx_out[r] = tid; }
  }
  __syncthreads();
  if (tid < BB) {
    int b = tid;
    float mx = -3.4e38f;
    for (int i = 0; i < KSEL; ++i) mx = fmaxf(mx, mvs[b][idxs[i]]);
    float s = 0.f;
    for (int i = 0; i < KSEL; ++i) s += expf(mvs[b][idxs[i]] - mx);
    float inv = 1.f / s;
    for (int i = 0; i < KSEL; ++i) wts_out[b * 64 + i] = expf(mvs[b][idxs[i]] - mx) * inv;
  }
  {
    float acc = 0.f;
    for (int m = 0; m < DD; ++m) acc += bv[m] * Wo[(size_t)m * DD + tid];
    bvo_out[tid] = acc + bo[tid];
  }
}

// ---------------- K3a: Wvo = Wv @ Wo (f32 scratch) ----------------
__global__ __launch_bounds__(256) void k_wvo(const float* __restrict__ Wv,
                                             const float* __restrict__ Wo,
                                             float* __restrict__ wvo) {
  int c = blockIdx.x * 256 + threadIdx.x;
  int j = blockIdx.y;
  float acc = 0.f;
#pragma unroll 8
  for (int m = 0; m < DD; ++m) acc += Wv[(size_t)j * DD + m] * Wo[(size_t)m * DD + c];
  wvo[(size_t)j * DD + c] = acc;
}

// ---------------- K3b: WvoT[c][j] = bf16(Wvo[j][c]) ----------------
__global__ __launch_bounds__(256) void k_transpose(const float* __restrict__ W,
                                                   ushort* __restrict__ WT) {
  __shared__ float t[32][33];
  int jt = blockIdx.x * 32, ct = blockIdx.y * 32;
  int tx = threadIdx.x, ty = threadIdx.y;
#pragma unroll
  for (int s = 0; s < 4; ++s)
    t[ty + 8 * s][tx] = W[(size_t)(jt + ty + 8 * s) * DD + ct + tx];
  __syncthreads();
#pragma unroll
  for (int s = 0; s < 4; ++s)
    WT[(size_t)(ct + ty + 8 * s) * DD + jt + tx] = f2bf(t[tx][ty + 8 * s]);
}

// -------- K4: vagg[b,l,c] = sum_i w[b,i] * v[b,(l+d_i)%L,c]  (bf16 out) --------
__global__ __launch_bounds__(256) void k_conv(const float* __restrict__ v,
                                              const int* __restrict__ idx,
                                              const float* __restrict__ wts,
                                              ushort* __restrict__ vagg) {
  __shared__ float vt[128][64];
  __shared__ float wl[KSEL];
  __shared__ int dl[KSEL];
  int lt = blockIdx.x;         // 64 l-tiles of 64 rows
  int ch0 = blockIdx.y * 64;   // 8 channel slices
  int b = blockIdx.z;
  int tid = threadIdx.x;
  int l0 = lt * 64;
  if (tid < KSEL) { wl[tid] = wts[b * 64 + tid]; dl[tid] = idx[tid]; }
#pragma unroll
  for (int it = 0; it < 8; ++it) {
    int ch = it * 256 + tid;
    int row = ch >> 4, cc = (ch & 15) * 4;
    int gl = l0 + row;
    if (gl >= LL) gl -= LL;
    *(float4*)&vt[row][cc] = *(const float4*)&v[((size_t)b * LL + gl) * DD + ch0 + cc];
  }
  __syncthreads();
  int c4 = (tid & 15) * 4;
  int r0 = tid >> 4;
#pragma unroll
  for (int jj = 0; jj < 4; ++jj) {
    int r = r0 + jj * 16;
    float a0 = 0, a1 = 0, a2 = 0, a3 = 0;
    for (int i = 0; i < KSEL; ++i) {
      float w = wl[i];
      const float4 vv = *(const float4*)&vt[r + dl[i]][c4];
      a0 += w * vv.x; a1 += w * vv.y; a2 += w * vv.z; a3 += w * vv.w;
    }
    ushort4 o;
    o.x = f2bf(a0); o.y = f2bf(a1); o.z = f2bf(a2); o.w = f2bf(a3);
    *(ushort4*)&vagg[((size_t)b * LL + l0 + r) * DD + ch0 + c4] = o;
  }
}

// -------- K5: out = vagg(bf16) @ Wvo(bf16, stored transposed) + bvo  (f32) --------
// 128x128 tile, BK=64, 4 waves (2x2), 16x16x32 bf16 MFMA, XOR-swizzled LDS.
__global__ __launch_bounds__(256) void k_gemm(const ushort* __restrict__ A,
                                              const ushort* __restrict__ BT,
                                              const float* __restrict__ bias,
                                              float* __restrict__ C) {
  __shared__ ushort lA[128 * 64];
  __shared__ ushort lB[128 * 64];
  int bcol = blockIdx.x * 128;
  int brow = blockIdx.y * 128;
  int tid = threadIdx.x;
  int lane = tid & 63, wid = tid >> 6;
  int wr = wid >> 1, wc = wid & 1;
  int r15 = lane & 15, g = lane >> 4;
  f32x4 acc[4][4] = {};
  for (int k0 = 0; k0 < DD; k0 += 64) {
#pragma unroll
    for (int it = 0; it < 4; ++it) {
      int ch = it * 256 + tid;  // lane-consecutive 16B chunks
      int row = ch >> 3;
      int clg = (ch & 7) ^ (row & 7);  // inverse-swizzled global source
      g2lds16(A + (size_t)(brow + row) * DD + k0 + clg * 8, &lA[ch * 8]);
      g2lds16(BT + (size_t)(bcol + row) * DD + k0 + clg * 8, &lB[ch * 8]);
    }
    asm volatile("s_waitcnt vmcnt(0)" ::: "memory");
    __syncthreads();
#pragma unroll
    for (int ks = 0; ks < 2; ++ks) {
      int kc = ks * 4 + g;  // logical 16B k-chunk for this lane group
      short8 av[4], bv[4];
#pragma unroll
      for (int m = 0; m < 4; ++m) {
        int row = wr * 64 + m * 16 + r15;
        av[m] = *(const short8*)&lA[(row * 8 + (kc ^ (row & 7))) * 8];
        int col = wc * 64 + m * 16 + r15;
        bv[m] = *(const short8*)&lB[(col * 8 + (kc ^ (col & 7))) * 8];
      }
#pragma unroll
      for (int m = 0; m < 4; ++m)
#pragma unroll
        for (int n = 0; n < 4; ++n)
          acc[m][n] = __builtin_amdgcn_mfma_f32_16x16x32_bf16(av[m], bv[n], acc[m][n], 0, 0, 0);
    }
    __syncthreads();
  }
#pragma unroll
  for (int n = 0; n < 4; ++n) {
    int col = bcol + wc * 64 + n * 16 + r15;
    float bc = bias[col];
#pragma unroll
    for (int m = 0; m < 4; ++m) {
      int row = brow + wr * 64 + m * 16 + g * 4;
#pragma unroll
      for (int r = 0; r < 4; ++r)
        C[(size_t)(row + r) * DD + col] = acc[m][n][r] + bc;
    }
  }
}

extern "C" void kernel_launch(void* const* d_in, const int* in_sizes, int n_in,
                              void* d_out, int out_size, void* d_ws, size_t ws_size,
                              hipStream_t stream) {
  const float* q  = (const float*)d_in[0];
  const float* k  = (const float*)d_in[1];
  const float* v  = (const float*)d_in[2];
  const float* Wq = (const float*)d_in[3];
  const float* bq = (const float*)d_in[4];
  const float* Wk = (const float*)d_in[5];
  const float* bk = (const float*)d_in[6];
  const float* Wv = (const float*)d_in[7];
  const float* bv = (const float*)d_in[8];
  const float* Wo = (const float*)d_in[9];
  const float* bo = (const float*)d_in[10];
  float* out = (float*)d_out;

  char* ws = (char*)d_ws;
  // workspace layout (needs ~36 MB)
  ushort* vagg  = (ushort*)(ws + 0x0);        // 32 MB bf16 [B*L*D]
  float* wvo32  = (float*)(ws + 0x2000000);   // 1 MB f32 [D][D]
  ushort* wvot  = (ushort*)(ws + 0x2100000);  // 512 KB bf16 [D][D] transposed
  float* qpart  = (float*)(ws + 0x2180000);   // 1 MB
  float* kpart  = (float*)(ws + 0x2280000);   // 1 MB
  float* sq     = (float*)(ws + 0x2380000);   // 16 KB
  float* sk     = (float*)(ws + 0x2384000);   // 16 KB
  int*   idx    = (int*)(ws + 0x2388800);     // 256 B
  float* wts    = (float*)(ws + 0x2388900);   // 2 KB
  float* bvo    = (float*)(ws + 0x2389100);   // 2 KB

  k_colsum<<<dim3(64, 8), 128, 0, stream>>>(q, k, qpart, kpart);
  k_colsum2<<<dim3(8), 128, 0, stream>>>(qpart, kpart, sq, sk);
  k_stats<<<dim3(1), 512, 0, stream>>>(sq, sk, Wq, bq, Wk, bk, bv, Wo, bo, idx, wts, bvo);
  k_wvo<<<dim3(2, 512), 256, 0, stream>>>(Wv, Wo, wvo32);
  k_transpose<<<dim3(16, 16), dim3(32, 8), 0, stream>>>(wvo32, wvot);
  k_conv<<<dim3(64, 8, 8), 256, 0, stream>>>(v, idx, wts, vagg);
  k_gemm<<<dim3(4, 256), 256, 0, stream>>>(vagg, wvot, bvo, out);
}

// Round 3
// 167.674 us; speedup vs baseline: 1.8502x; 1.8502x over previous
//
#include <hip/hip_runtime.h>
#include <hip/hip_bf16.h>

#define LL 4096
#define DD 512
#define BB 8
#define KSEL 41

typedef __attribute__((ext_vector_type(4))) float f32x4;
typedef __attribute__((ext_vector_type(8))) short short8;

__device__ __forceinline__ ushort f2bf(float x) {
  __hip_bfloat16 h = __float2bfloat16(x);
  return *reinterpret_cast<ushort*>(&h);
}

__device__ __forceinline__ void g2lds16(const void* g, void* l) {
  __builtin_amdgcn_global_load_lds(
      (const __attribute__((address_space(1))) unsigned int*)g,
      (__attribute__((address_space(3))) unsigned int*)l, 16, 0, 0);
}

// ---------------- K1a: partial column sums of q,k over L ----------------
__global__ __launch_bounds__(128) void k_colsum(const float* __restrict__ q,
                                                const float* __restrict__ kk,
                                                float* __restrict__ qpart,
                                                float* __restrict__ kpart) {
  int lc = blockIdx.x, b = blockIdx.y;
  int c4 = threadIdx.x * 4;
  float aq0 = 0, aq1 = 0, aq2 = 0, aq3 = 0, ak0 = 0, ak1 = 0, ak2 = 0, ak3 = 0;
  const float* qp = q + ((size_t)b * LL + (size_t)lc * 64) * DD + c4;
  const float* kp = kk + ((size_t)b * LL + (size_t)lc * 64) * DD + c4;
#pragma unroll 4
  for (int l = 0; l < 64; ++l) {
    float4 x = *(const float4*)(qp + (size_t)l * DD);
    float4 y = *(const float4*)(kp + (size_t)l * DD);
    aq0 += x.x; aq1 += x.y; aq2 += x.z; aq3 += x.w;
    ak0 += y.x; ak1 += y.y; ak2 += y.z; ak3 += y.w;
  }
  float4 oq = {aq0, aq1, aq2, aq3};
  float4 ok = {ak0, ak1, ak2, ak3};
  *(float4*)&qpart[((size_t)b * 64 + lc) * DD + c4] = oq;
  *(float4*)&kpart[((size_t)b * 64 + lc) * DD + c4] = ok;
}

// ---------------- K1b: reduce partials -> sq, sk [B][D] ----------------
__global__ __launch_bounds__(128) void k_colsum2(const float* __restrict__ qpart,
                                                 const float* __restrict__ kpart,
                                                 float* __restrict__ sq,
                                                 float* __restrict__ sk) {
  int b = blockIdx.x;
  int c4 = threadIdx.x * 4;
  float aq0 = 0, aq1 = 0, aq2 = 0, aq3 = 0, ak0 = 0, ak1 = 0, ak2 = 0, ak3 = 0;
  for (int p = 0; p < 64; ++p) {
    float4 x = *(const float4*)&qpart[((size_t)b * 64 + p) * DD + c4];
    float4 y = *(const float4*)&kpart[((size_t)b * 64 + p) * DD + c4];
    aq0 += x.x; aq1 += x.y; aq2 += x.z; aq3 += x.w;
    ak0 += y.x; ak1 += y.y; ak2 += y.z; ak3 += y.w;
  }
  float4 oq = {aq0, aq1, aq2, aq3};
  float4 ok = {ak0, ak1, ak2, ak3};
  *(float4*)&sq[(size_t)b * DD + c4] = oq;
  *(float4*)&sk[(size_t)b * DD + c4] = ok;
}

// ------- K2a: parallel partial projections: sq@Wq, sk@Wk, bv@Wo -------
// grid (8 j-chunks of 64, 3 matrices), 256 threads (each thread: 2 columns)
__global__ __launch_bounds__(256) void k_proj(
    const float* __restrict__ sq, const float* __restrict__ sk,
    const float* __restrict__ Wq, const float* __restrict__ Wk,
    const float* __restrict__ bv, const float* __restrict__ Wo,
    float* __restrict__ partQ, float* __restrict__ partK,
    float* __restrict__ partO) {
  int jc = blockIdx.x;     // 8 chunks of 64 rows of W
  int which = blockIdx.y;  // 0=q, 1=k, 2=o
  int tid = threadIdx.x;
  int j0 = jc * 64;
  if (which == 2) {
    float a0 = 0.f, a1 = 0.f;
    for (int j = 0; j < 64; ++j) {
      float b = bv[j0 + j];
      a0 += b * Wo[(size_t)(j0 + j) * DD + tid];
      a1 += b * Wo[(size_t)(j0 + j) * DD + tid + 256];
    }
    partO[(size_t)jc * DD + tid] = a0;
    partO[(size_t)jc * DD + tid + 256] = a1;
    return;
  }
  const float* s = (which == 0) ? sq : sk;
  const float* W = (which == 0) ? Wq : Wk;
  __shared__ float ss[BB][64];
  // 256 threads but BB*64=512 entries: strided loop (R2 bug was `if (tid<512)`)
  for (int t = tid; t < BB * 64; t += 256)
    ss[t >> 6][t & 63] = s[(size_t)(t >> 6) * DD + j0 + (t & 63)];
  __syncthreads();
  float a[BB][2];
#pragma unroll
  for (int b = 0; b < BB; ++b) { a[b][0] = 0.f; a[b][1] = 0.f; }
  for (int j = 0; j < 64; ++j) {
    float w0 = W[(size_t)(j0 + j) * DD + tid];
    float w1 = W[(size_t)(j0 + j) * DD + tid + 256];
#pragma unroll
    for (int b = 0; b < BB; ++b) {
      float sv = ss[b][j];
      a[b][0] += sv * w0;
      a[b][1] += sv * w1;
    }
  }
  float* part = (which == 0) ? partQ : partK;
#pragma unroll
  for (int b = 0; b < BB; ++b) {
    part[((size_t)jc * BB + b) * DD + tid] = a[b][0];
    part[((size_t)jc * BB + b) * DD + tid + 256] = a[b][1];
  }
}

// ------- K2b: reduce partials, mean_value, top-41, softmax, bvo -------
__global__ __launch_bounds__(512) void k_stats2(
    const float* __restrict__ partQ, const float* __restrict__ partK,
    const float* __restrict__ partO,
    const float* __restrict__ bq, const float* __restrict__ bk,
    const float* __restrict__ bo,
    int* __restrict__ idx_out, float* __restrict__ wts_out,
    float* __restrict__ bvo_out) {
  __shared__ float Sq[BB][DD];
  __shared__ float Sk[BB][DD];
  __shared__ float mvs[BB][64];
  __shared__ float mab[64];
  __shared__ int idxs[64];
  int tid = threadIdx.x;
  float bqv = bq[tid] * (float)LL, bkv = bk[tid] * (float)LL;
#pragma unroll
  for (int b = 0; b < BB; ++b) {
    float aq = 0.f, ak = 0.f;
#pragma unroll
    for (int jc = 0; jc < 8; ++jc) {
      aq += partQ[((size_t)jc * BB + b) * DD + tid];
      ak += partK[((size_t)jc * BB + b) * DD + tid];
    }
    Sq[b][tid] = aq + bqv;
    Sk[b][tid] = ak + bkv;
  }
  {
    float ao = 0.f;
#pragma unroll
    for (int jc = 0; jc < 8; ++jc) ao += partO[(size_t)jc * DD + tid];
    bvo_out[tid] = ao + bo[tid];
  }
  __syncthreads();
  {
    int b = tid >> 6, d = tid & 63;
    float s = 0.f;
#pragma unroll
    for (int h = 0; h < 8; ++h) s += Sq[b][h * 64 + d] * Sk[b][h * 64 + d];
    mvs[b][d] = s * (1.0f / ((float)LL * 8.0f));
  }
  __syncthreads();
  if (tid < 64) {
    float s = 0.f;
#pragma unroll
    for (int b = 0; b < BB; ++b) s += mvs[b][tid];
    mab[tid] = s * 0.125f;
  }
  __syncthreads();
  if (tid < 64) {
    float x = mab[tid];
    int r = 0;
    for (int d = 0; d < 64; ++d) {
      float y = mab[d];
      r += (y > x || (y == x && d < tid)) ? 1 : 0;
    }
    if (r < KSEL) { idxs[r] = tid; idx_out[r] = tid; }
  }
  __syncthreads();
  if (tid < BB) {
    int b = tid;
    float mx = -3.4e38f;
    for (int i = 0; i < KSEL; ++i) mx = fmaxf(mx, mvs[b][idxs[i]]);
    float s = 0.f;
    for (int i = 0; i < KSEL; ++i) s += expf(mvs[b][idxs[i]] - mx);
    float inv = 1.f / s;
    for (int i = 0; i < KSEL; ++i) wts_out[b * 64 + i] = expf(mvs[b][idxs[i]] - mx) * inv;
  }
}

// ---------------- K3a: Wvo = Wv @ Wo (f32 scratch) ----------------
__global__ __launch_bounds__(256) void k_wvo(const float* __restrict__ Wv,
                                             const float* __restrict__ Wo,
                                             float* __restrict__ wvo) {
  int c = blockIdx.x * 256 + threadIdx.x;
  int j = blockIdx.y;
  float acc = 0.f;
#pragma unroll 8
  for (int m = 0; m < DD; ++m) acc += Wv[(size_t)j * DD + m] * Wo[(size_t)m * DD + c];
  wvo[(size_t)j * DD + c] = acc;
}

// ---------------- K3b: WvoT[c][j] = bf16(Wvo[j][c]) ----------------
__global__ __launch_bounds__(256) void k_transpose(const float* __restrict__ W,
                                                   ushort* __restrict__ WT) {
  __shared__ float t[32][33];
  int jt = blockIdx.x * 32, ct = blockIdx.y * 32;
  int tx = threadIdx.x, ty = threadIdx.y;
#pragma unroll
  for (int s = 0; s < 4; ++s)
    t[ty + 8 * s][tx] = W[(size_t)(jt + ty + 8 * s) * DD + ct + tx];
  __syncthreads();
#pragma unroll
  for (int s = 0; s < 4; ++s)
    WT[(size_t)(ct + ty + 8 * s) * DD + jt + tx] = f2bf(t[tx][ty + 8 * s]);
}

// -------- K4: vagg[b,l,c] = sum_i w[b,i] * v[b,(l+d_i)%L,c]  (bf16 out) --------
__global__ __launch_bounds__(256) void k_conv(const float* __restrict__ v,
                                              const int* __restrict__ idx,
                                              const float* __restrict__ wts,
                                              ushort* __restrict__ vagg) {
  __shared__ float vt[128][64];
  __shared__ float wl[KSEL];
  __shared__ int dl[KSEL];
  int lt = blockIdx.x;         // 64 l-tiles of 64 rows
  int ch0 = blockIdx.y * 64;   // 8 channel slices
  int b = blockIdx.z;
  int tid = threadIdx.x;
  int l0 = lt * 64;
  if (tid < KSEL) { wl[tid] = wts[b * 64 + tid]; dl[tid] = idx[tid]; }
#pragma unroll
  for (int it = 0; it < 8; ++it) {
    int ch = it * 256 + tid;
    int row = ch >> 4, cc = (ch & 15) * 4;
    int gl = l0 + row;
    if (gl >= LL) gl -= LL;
    *(float4*)&vt[row][cc] = *(const float4*)&v[((size_t)b * LL + gl) * DD + ch0 + cc];
  }
  __syncthreads();
  int c4 = (tid & 15) * 4;
  int r0 = tid >> 4;
#pragma unroll
  for (int jj = 0; jj < 4; ++jj) {
    int r = r0 + jj * 16;
    float a0 = 0, a1 = 0, a2 = 0, a3 = 0;
    for (int i = 0; i < KSEL; ++i) {
      float w = wl[i];
      const float4 vv = *(const float4*)&vt[r + dl[i]][c4];
      a0 += w * vv.x; a1 += w * vv.y; a2 += w * vv.z; a3 += w * vv.w;
    }
    ushort4 o;
    o.x = f2bf(a0); o.y = f2bf(a1); o.z = f2bf(a2); o.w = f2bf(a3);
    *(ushort4*)&vagg[((size_t)b * LL + l0 + r) * DD + ch0 + c4] = o;
  }
}

// -------- K5: out = vagg(bf16) @ Wvo(bf16, stored transposed) + bvo  (f32) --------
// 128x128 tile, BK=64, 4 waves (2x2), 16x16x32 bf16 MFMA, XOR-swizzled LDS.
__global__ __launch_bounds__(256) void k_gemm(const ushort* __restrict__ A,
                                              const ushort* __restrict__ BT,
                                              const float* __restrict__ bias,
                                              float* __restrict__ C) {
  __shared__ ushort lA[128 * 64];
  __shared__ ushort lB[128 * 64];
  int bcol = blockIdx.x * 128;
  int brow = blockIdx.y * 128;
  int tid = threadIdx.x;
  int lane = tid & 63, wid = tid >> 6;
  int wr = wid >> 1, wc = wid & 1;
  int r15 = lane & 15, g = lane >> 4;
  f32x4 acc[4][4] = {};
  for (int k0 = 0; k0 < DD; k0 += 64) {
#pragma unroll
    for (int it = 0; it < 4; ++it) {
      int ch = it * 256 + tid;  // lane-consecutive 16B chunks
      int row = ch >> 3;
      int clg = (ch & 7) ^ (row & 7);  // inverse-swizzled global source
      g2lds16(A + (size_t)(brow + row) * DD + k0 + clg * 8, &lA[ch * 8]);
      g2lds16(BT + (size_t)(bcol + row) * DD + k0 + clg * 8, &lB[ch * 8]);
    }
    asm volatile("s_waitcnt vmcnt(0)" ::: "memory");
    __syncthreads();
#pragma unroll
    for (int ks = 0; ks < 2; ++ks) {
      int kc = ks * 4 + g;  // logical 16B k-chunk for this lane group
      short8 av[4], bv[4];
#pragma unroll
      for (int m = 0; m < 4; ++m) {
        int row = wr * 64 + m * 16 + r15;
        av[m] = *(const short8*)&lA[(row * 8 + (kc ^ (row & 7))) * 8];
        int col = wc * 64 + m * 16 + r15;
        bv[m] = *(const short8*)&lB[(col * 8 + (kc ^ (col & 7))) * 8];
      }
#pragma unroll
      for (int m = 0; m < 4; ++m)
#pragma unroll
        for (int n = 0; n < 4; ++n)
          acc[m][n] = __builtin_amdgcn_mfma_f32_16x16x32_bf16(av[m], bv[n], acc[m][n], 0, 0, 0);
    }
    __syncthreads();
  }
#pragma unroll
  for (int n = 0; n < 4; ++n) {
    int col = bcol + wc * 64 + n * 16 + r15;
    float bc = bias[col];
#pragma unroll
    for (int m = 0; m < 4; ++m) {
      int row = brow + wr * 64 + m * 16 + g * 4;
#pragma unroll
      for (int r = 0; r < 4; ++r)
        C[(size_t)(row + r) * DD + col] = acc[m][n][r] + bc;
    }
  }
}

extern "C" void kernel_launch(void* const* d_in, const int* in_sizes, int n_in,
                              void* d_out, int out_size, void* d_ws, size_t ws_size,
                              hipStream_t stream) {
  const float* q  = (const float*)d_in[0];
  const float* k  = (const float*)d_in[1];
  const float* v  = (const float*)d_in[2];
  const float* Wq = (const float*)d_in[3];
  const float* bq = (const float*)d_in[4];
  const float* Wk = (const float*)d_in[5];
  const float* bk = (const float*)d_in[6];
  const float* Wv = (const float*)d_in[7];
  const float* bv = (const float*)d_in[8];
  const float* Wo = (const float*)d_in[9];
  const float* bo = (const float*)d_in[10];
  float* out = (float*)d_out;

  char* ws = (char*)d_ws;
  // workspace layout (~37.3 MB; partials overlay the dead qpart region)
  ushort* vagg  = (ushort*)(ws + 0x0);        // 32 MB bf16 [B*L*D]
  float* wvo32  = (float*)(ws + 0x2000000);   // 1 MB f32 [D][D]
  ushort* wvot  = (ushort*)(ws + 0x2100000);  // 512 KB bf16 [D][D] transposed
  float* qpart  = (float*)(ws + 0x2180000);   // 1 MB (dead after k_colsum2)
  float* kpart  = (float*)(ws + 0x2280000);   // 1 MB (dead after k_colsum2)
  float* sq     = (float*)(ws + 0x2380000);   // 16 KB
  float* sk     = (float*)(ws + 0x2384000);   // 16 KB
  int*   idx    = (int*)(ws + 0x2388800);     // 256 B
  float* wts    = (float*)(ws + 0x2388900);   // 2 KB
  float* bvo    = (float*)(ws + 0x2389100);   // 2 KB
  // partials overlay qpart (safe: stream-ordered after k_colsum2 consumed it)
  float* partQ  = (float*)(ws + 0x2180000);   // 128 KB [8][8][512]
  float* partK  = (float*)(ws + 0x21A0000);   // 128 KB [8][8][512]
  float* partO  = (float*)(ws + 0x21C0000);   // 16 KB  [8][512]

  k_colsum<<<dim3(64, 8), 128, 0, stream>>>(q, k, qpart, kpart);
  k_colsum2<<<dim3(8), 128, 0, stream>>>(qpart, kpart, sq, sk);
  k_proj<<<dim3(8, 3), 256, 0, stream>>>(sq, sk, Wq, Wk, bv, Wo, partQ, partK, partO);
  k_stats2<<<dim3(1), 512, 0, stream>>>(partQ, partK, partO, bq, bk, bo, idx, wts, bvo);
  k_wvo<<<dim3(2, 512), 256, 0, stream>>>(Wv, Wo, wvo32);
  k_transpose<<<dim3(16, 16), dim3(32, 8), 0, stream>>>(wvo32, wvot);
  k_conv<<<dim3(64, 8, 8), 256, 0, stream>>>(v, idx, wts, vagg);
  k_gemm<<<dim3(4, 256), 256, 0, stream>>>(vagg, wvot, bvo, out);
}

// Round 4
// 166.009 us; speedup vs baseline: 1.8687x; 1.0100x over previous
//
#include <hip/hip_runtime.h>
#include <hip/hip_bf16.h>

#define LL 4096
#define DD 512
#define BB 8
#define KSEL 41

typedef __attribute__((ext_vector_type(4))) float f32x4;
typedef __attribute__((ext_vector_type(8))) short short8;

__device__ __forceinline__ ushort f2bf(float x) {
  __hip_bfloat16 h = __float2bfloat16(x);
  return *reinterpret_cast<ushort*>(&h);
}

__device__ __forceinline__ void g2lds16(const void* g, void* l) {
  __builtin_amdgcn_global_load_lds(
      (const __attribute__((address_space(1))) unsigned int*)g,
      (__attribute__((address_space(3))) unsigned int*)l, 16, 0, 0);
}

// ---------------- K1a: partial column sums of q,k over L ----------------
__global__ __launch_bounds__(128) void k_colsum(const float* __restrict__ q,
                                                const float* __restrict__ kk,
                                                float* __restrict__ qpart,
                                                float* __restrict__ kpart) {
  int lc = blockIdx.x, b = blockIdx.y;
  int c4 = threadIdx.x * 4;
  float aq0 = 0, aq1 = 0, aq2 = 0, aq3 = 0, ak0 = 0, ak1 = 0, ak2 = 0, ak3 = 0;
  const float* qp = q + ((size_t)b * LL + (size_t)lc * 64) * DD + c4;
  const float* kp = kk + ((size_t)b * LL + (size_t)lc * 64) * DD + c4;
#pragma unroll 4
  for (int l = 0; l < 64; ++l) {
    float4 x = *(const float4*)(qp + (size_t)l * DD);
    float4 y = *(const float4*)(kp + (size_t)l * DD);
    aq0 += x.x; aq1 += x.y; aq2 += x.z; aq3 += x.w;
    ak0 += y.x; ak1 += y.y; ak2 += y.z; ak3 += y.w;
  }
  float4 oq = {aq0, aq1, aq2, aq3};
  float4 ok = {ak0, ak1, ak2, ak3};
  *(float4*)&qpart[((size_t)b * 64 + lc) * DD + c4] = oq;
  *(float4*)&kpart[((size_t)b * 64 + lc) * DD + c4] = ok;
}

// ---------------- K1b: reduce partials -> sq, sk [B][D] ----------------
__global__ __launch_bounds__(128) void k_colsum2(const float* __restrict__ qpart,
                                                 const float* __restrict__ kpart,
                                                 float* __restrict__ sq,
                                                 float* __restrict__ sk) {
  int b = blockIdx.x;
  int c4 = threadIdx.x * 4;
  float aq0 = 0, aq1 = 0, aq2 = 0, aq3 = 0, ak0 = 0, ak1 = 0, ak2 = 0, ak3 = 0;
  for (int p = 0; p < 64; ++p) {
    float4 x = *(const float4*)&qpart[((size_t)b * 64 + p) * DD + c4];
    float4 y = *(const float4*)&kpart[((size_t)b * 64 + p) * DD + c4];
    aq0 += x.x; aq1 += x.y; aq2 += x.z; aq3 += x.w;
    ak0 += y.x; ak1 += y.y; ak2 += y.z; ak3 += y.w;
  }
  float4 oq = {aq0, aq1, aq2, aq3};
  float4 ok = {ak0, ak1, ak2, ak3};
  *(float4*)&sq[(size_t)b * DD + c4] = oq;
  *(float4*)&sk[(size_t)b * DD + c4] = ok;
}

// ------- K2a: parallel partial projections: sq@Wq, sk@Wk, bv@Wo -------
__global__ __launch_bounds__(256) void k_proj(
    const float* __restrict__ sq, const float* __restrict__ sk,
    const float* __restrict__ Wq, const float* __restrict__ Wk,
    const float* __restrict__ bv, const float* __restrict__ Wo,
    float* __restrict__ partQ, float* __restrict__ partK,
    float* __restrict__ partO) {
  int jc = blockIdx.x;     // 8 chunks of 64 rows of W
  int which = blockIdx.y;  // 0=q, 1=k, 2=o
  int tid = threadIdx.x;
  int j0 = jc * 64;
  if (which == 2) {
    float a0 = 0.f, a1 = 0.f;
    for (int j = 0; j < 64; ++j) {
      float b = bv[j0 + j];
      a0 += b * Wo[(size_t)(j0 + j) * DD + tid];
      a1 += b * Wo[(size_t)(j0 + j) * DD + tid + 256];
    }
    partO[(size_t)jc * DD + tid] = a0;
    partO[(size_t)jc * DD + tid + 256] = a1;
    return;
  }
  const float* s = (which == 0) ? sq : sk;
  const float* W = (which == 0) ? Wq : Wk;
  __shared__ float ss[BB][64];
  for (int t = tid; t < BB * 64; t += 256)
    ss[t >> 6][t & 63] = s[(size_t)(t >> 6) * DD + j0 + (t & 63)];
  __syncthreads();
  float a[BB][2];
#pragma unroll
  for (int b = 0; b < BB; ++b) { a[b][0] = 0.f; a[b][1] = 0.f; }
  for (int j = 0; j < 64; ++j) {
    float w0 = W[(size_t)(j0 + j) * DD + tid];
    float w1 = W[(size_t)(j0 + j) * DD + tid + 256];
#pragma unroll
    for (int b = 0; b < BB; ++b) {
      float sv = ss[b][j];
      a[b][0] += sv * w0;
      a[b][1] += sv * w1;
    }
  }
  float* part = (which == 0) ? partQ : partK;
#pragma unroll
  for (int b = 0; b < BB; ++b) {
    part[((size_t)jc * BB + b) * DD + tid] = a[b][0];
    part[((size_t)jc * BB + b) * DD + tid + 256] = a[b][1];
  }
}

// ------- K2b: reduce partials, mean_value, top-41, softmax, bvo -------
__global__ __launch_bounds__(512) void k_stats2(
    const float* __restrict__ partQ, const float* __restrict__ partK,
    const float* __restrict__ partO,
    const float* __restrict__ bq, const float* __restrict__ bk,
    const float* __restrict__ bo,
    int* __restrict__ idx_out, float* __restrict__ wts_out,
    float* __restrict__ bvo_out) {
  __shared__ float Sq[BB][DD];
  __shared__ float Sk[BB][DD];
  __shared__ float mvs[BB][64];
  __shared__ float mab[64];
  __shared__ int idxs[64];
  int tid = threadIdx.x;
  float bqv = bq[tid] * (float)LL, bkv = bk[tid] * (float)LL;
#pragma unroll
  for (int b = 0; b < BB; ++b) {
    float aq = 0.f, ak = 0.f;
#pragma unroll
    for (int jc = 0; jc < 8; ++jc) {
      aq += partQ[((size_t)jc * BB + b) * DD + tid];
      ak += partK[((size_t)jc * BB + b) * DD + tid];
    }
    Sq[b][tid] = aq + bqv;
    Sk[b][tid] = ak + bkv;
  }
  {
    float ao = 0.f;
#pragma unroll
    for (int jc = 0; jc < 8; ++jc) ao += partO[(size_t)jc * DD + tid];
    bvo_out[tid] = ao + bo[tid];
  }
  __syncthreads();
  {
    int b = tid >> 6, d = tid & 63;
    float s = 0.f;
#pragma unroll
    for (int h = 0; h < 8; ++h) s += Sq[b][h * 64 + d] * Sk[b][h * 64 + d];
    mvs[b][d] = s * (1.0f / ((float)LL * 8.0f));
  }
  __syncthreads();
  if (tid < 64) {
    float s = 0.f;
#pragma unroll
    for (int b = 0; b < BB; ++b) s += mvs[b][tid];
    mab[tid] = s * 0.125f;
  }
  __syncthreads();
  if (tid < 64) {
    float x = mab[tid];
    int r = 0;
    for (int d = 0; d < 64; ++d) {
      float y = mab[d];
      r += (y > x || (y == x && d < tid)) ? 1 : 0;
    }
    if (r < KSEL) { idxs[r] = tid; idx_out[r] = tid; }
  }
  __syncthreads();
  if (tid < BB) {
    int b = tid;
    float mx = -3.4e38f;
    for (int i = 0; i < KSEL; ++i) mx = fmaxf(mx, mvs[b][idxs[i]]);
    float s = 0.f;
    for (int i = 0; i < KSEL; ++i) s += expf(mvs[b][idxs[i]] - mx);
    float inv = 1.f / s;
    for (int i = 0; i < KSEL; ++i) wts_out[b * 64 + i] = expf(mvs[b][idxs[i]] - mx) * inv;
  }
}

// ------- K3: Wvo^T (bf16) = (Wv @ Wo)^T, fused, no f32 round trip -------
// grid (2, 64): 256 cols x 8 j-rows per block.
__global__ __launch_bounds__(256) void k_wvot(const float* __restrict__ Wv,
                                              const float* __restrict__ Wo,
                                              ushort* __restrict__ WT) {
  __shared__ float wv[8][512];  // 16 KB
  int tid = threadIdx.x;
  int c = blockIdx.x * 256 + tid;
  int j0 = blockIdx.y * 8;
  for (int t = tid; t < 8 * 512; t += 256)
    wv[t >> 9][t & 511] = Wv[(size_t)(j0 + (t >> 9)) * DD + (t & 511)];
  __syncthreads();
  float acc[8] = {0, 0, 0, 0, 0, 0, 0, 0};
  for (int m = 0; m < DD; ++m) {
    float wo = Wo[(size_t)m * DD + c];
#pragma unroll
    for (int j = 0; j < 8; ++j) acc[j] += wv[j][m] * wo;
  }
  ushort4 o0, o1;
  o0.x = f2bf(acc[0]); o0.y = f2bf(acc[1]); o0.z = f2bf(acc[2]); o0.w = f2bf(acc[3]);
  o1.x = f2bf(acc[4]); o1.y = f2bf(acc[5]); o1.z = f2bf(acc[6]); o1.w = f2bf(acc[7]);
  *(ushort4*)&WT[(size_t)c * DD + j0] = o0;
  *(ushort4*)&WT[(size_t)c * DD + j0 + 4] = o1;
}

// -------- K4: vagg[b,l,c] = sum_i w[b,i] * v[b,(l+d_i)%L,c]  (bf16 out) --------
// v staged in LDS as bf16 (halves LDS bytes vs f32: the measured bottleneck).
__global__ __launch_bounds__(256) void k_conv(const float* __restrict__ v,
                                              const int* __restrict__ idx,
                                              const float* __restrict__ wts,
                                              ushort* __restrict__ vagg) {
  __shared__ ushort vt[128][64];  // 16 KB bf16
  __shared__ float wl[KSEL];
  __shared__ int dl[KSEL];
  int lt = blockIdx.x;         // 64 l-tiles of 64 rows
  int ch0 = blockIdx.y * 64;   // 8 channel slices
  int b = blockIdx.z;
  int tid = threadIdx.x;
  int l0 = lt * 64;
  if (tid < KSEL) { wl[tid] = wts[b * 64 + tid]; dl[tid] = idx[tid]; }
#pragma unroll
  for (int it = 0; it < 8; ++it) {
    int e = it * 256 + tid;  // 2048 float4-slots = 128 rows x 16 slots
    int row = e >> 4, c = (e & 15) * 4;
    int gl = l0 + row;
    if (gl >= LL) gl -= LL;
    float4 x = *(const float4*)&v[((size_t)b * LL + gl) * DD + ch0 + c];
    ushort4 o;
    o.x = f2bf(x.x); o.y = f2bf(x.y); o.z = f2bf(x.z); o.w = f2bf(x.w);
    *(ushort4*)&vt[row][c] = o;
  }
  __syncthreads();
  int cg = (tid & 7) * 8;  // 8-channel group
  int r0 = tid >> 3;       // 0..31 (rows r0 and r0+32)
  float acc[2][8];
#pragma unroll
  for (int jj = 0; jj < 2; ++jj)
#pragma unroll
    for (int t = 0; t < 8; ++t) acc[jj][t] = 0.f;
  for (int i = 0; i < KSEL; ++i) {
    float w = wl[i];
    int d = dl[i];
#pragma unroll
    for (int jj = 0; jj < 2; ++jj) {
      int row = r0 + jj * 32 + d;
      union { short8 s; unsigned int u[4]; } uu;
      uu.s = *(const short8*)&vt[row][cg];
#pragma unroll
      for (int t = 0; t < 4; ++t) {
        float lo = __uint_as_float(uu.u[t] << 16);
        float hi = __uint_as_float(uu.u[t] & 0xFFFF0000u);
        acc[jj][2 * t] += w * lo;
        acc[jj][2 * t + 1] += w * hi;
      }
    }
  }
#pragma unroll
  for (int jj = 0; jj < 2; ++jj) {
    int r = r0 + jj * 32;
    union { short8 s; ushort us[8]; } oo;
#pragma unroll
    for (int t = 0; t < 8; ++t) oo.us[t] = f2bf(acc[jj][t]);
    *(short8*)&vagg[((size_t)b * LL + l0 + r) * DD + ch0 + cg] = oo.s;
  }
}

// -------- K5: out = vagg(bf16) @ Wvo(bf16, stored transposed) + bvo  (f32) --------
__global__ __launch_bounds__(256) void k_gemm(const ushort* __restrict__ A,
                                              const ushort* __restrict__ BT,
                                              const float* __restrict__ bias,
                                              float* __restrict__ C) {
  __shared__ ushort lA[128 * 64];
  __shared__ ushort lB[128 * 64];
  int bcol = blockIdx.x * 128;
  int brow = blockIdx.y * 128;
  int tid = threadIdx.x;
  int lane = tid & 63, wid = tid >> 6;
  int wr = wid >> 1, wc = wid & 1;
  int r15 = lane & 15, g = lane >> 4;
  f32x4 acc[4][4] = {};
  for (int k0 = 0; k0 < DD; k0 += 64) {
#pragma unroll
    for (int it = 0; it < 4; ++it) {
      int ch = it * 256 + tid;  // lane-consecutive 16B chunks
      int row = ch >> 3;
      int clg = (ch & 7) ^ (row & 7);  // inverse-swizzled global source
      g2lds16(A + (size_t)(brow + row) * DD + k0 + clg * 8, &lA[ch * 8]);
      g2lds16(BT + (size_t)(bcol + row) * DD + k0 + clg * 8, &lB[ch * 8]);
    }
    asm volatile("s_waitcnt vmcnt(0)" ::: "memory");
    __syncthreads();
#pragma unroll
    for (int ks = 0; ks < 2; ++ks) {
      int kc = ks * 4 + g;  // logical 16B k-chunk for this lane group
      short8 av[4], bv[4];
#pragma unroll
      for (int m = 0; m < 4; ++m) {
        int row = wr * 64 + m * 16 + r15;
        av[m] = *(const short8*)&lA[(row * 8 + (kc ^ (row & 7))) * 8];
        int col = wc * 64 + m * 16 + r15;
        bv[m] = *(const short8*)&lB[(col * 8 + (kc ^ (col & 7))) * 8];
      }
#pragma unroll
      for (int m = 0; m < 4; ++m)
#pragma unroll
        for (int n = 0; n < 4; ++n)
          acc[m][n] = __builtin_amdgcn_mfma_f32_16x16x32_bf16(av[m], bv[n], acc[m][n], 0, 0, 0);
    }
    __syncthreads();
  }
#pragma unroll
  for (int n = 0; n < 4; ++n) {
    int col = bcol + wc * 64 + n * 16 + r15;
    float bc = bias[col];
#pragma unroll
    for (int m = 0; m < 4; ++m) {
      int row = brow + wr * 64 + m * 16 + g * 4;
#pragma unroll
      for (int r = 0; r < 4; ++r)
        C[(size_t)(row + r) * DD + col] = acc[m][n][r] + bc;
    }
  }
}

extern "C" void kernel_launch(void* const* d_in, const int* in_sizes, int n_in,
                              void* d_out, int out_size, void* d_ws, size_t ws_size,
                              hipStream_t stream) {
  const float* q  = (const float*)d_in[0];
  const float* k  = (const float*)d_in[1];
  const float* v  = (const float*)d_in[2];
  const float* Wq = (const float*)d_in[3];
  const float* bq = (const float*)d_in[4];
  const float* Wk = (const float*)d_in[5];
  const float* bk = (const float*)d_in[6];
  const float* Wv = (const float*)d_in[7];
  const float* bv = (const float*)d_in[8];
  const float* Wo = (const float*)d_in[9];
  const float* bo = (const float*)d_in[10];
  float* out = (float*)d_out;

  char* ws = (char*)d_ws;
  ushort* vagg  = (ushort*)(ws + 0x0);        // 32 MB bf16 [B*L*D]
  ushort* wvot  = (ushort*)(ws + 0x2100000);  // 512 KB bf16 [D][D] transposed
  float* qpart  = (float*)(ws + 0x2180000);   // 1 MB (dead after k_colsum2)
  float* kpart  = (float*)(ws + 0x2280000);   // 1 MB (dead after k_colsum2)
  float* sq     = (float*)(ws + 0x2380000);   // 16 KB
  float* sk     = (float*)(ws + 0x2384000);   // 16 KB
  int*   idx    = (int*)(ws + 0x2388800);     // 256 B
  float* wts    = (float*)(ws + 0x2388900);   // 2 KB
  float* bvo    = (float*)(ws + 0x2389100);   // 2 KB
  float* partQ  = (float*)(ws + 0x2180000);   // 128 KB (overlays dead qpart)
  float* partK  = (float*)(ws + 0x21A0000);   // 128 KB
  float* partO  = (float*)(ws + 0x21C0000);   // 16 KB

  k_colsum<<<dim3(64, 8), 128, 0, stream>>>(q, k, qpart, kpart);
  k_colsum2<<<dim3(8), 128, 0, stream>>>(qpart, kpart, sq, sk);
  k_proj<<<dim3(8, 3), 256, 0, stream>>>(sq, sk, Wq, Wk, bv, Wo, partQ, partK, partO);
  k_stats2<<<dim3(1), 512, 0, stream>>>(partQ, partK, partO, bq, bk, bo, idx, wts, bvo);
  k_wvot<<<dim3(2, 64), 256, 0, stream>>>(Wv, Wo, wvot);
  k_conv<<<dim3(64, 8, 8), 256, 0, stream>>>(v, idx, wts, vagg);
  k_gemm<<<dim3(4, 256), 256, 0, stream>>>(vagg, wvot, bvo, out);
}

// Round 5
// 151.205 us; speedup vs baseline: 2.0517x; 1.0979x over previous
//
#include <hip/hip_runtime.h>
#include <hip/hip_bf16.h>

#define LL 4096
#define DD 512
#define BB 8
#define KSEL 41

typedef __attribute__((ext_vector_type(4))) float f32x4;
typedef __attribute__((ext_vector_type(8))) short short8;

__device__ __forceinline__ ushort f2bf(float x) {
  __hip_bfloat16 h = __float2bfloat16(x);
  return *reinterpret_cast<ushort*>(&h);
}

__device__ __forceinline__ void g2lds16(const void* g, void* l) {
  __builtin_amdgcn_global_load_lds(
      (const __attribute__((address_space(1))) unsigned int*)g,
      (__attribute__((address_space(3))) unsigned int*)l, 16, 0, 0);
}

// ---------------- K1a: partial column sums of q,k over L ----------------
__global__ __launch_bounds__(128) void k_colsum(const float* __restrict__ q,
                                                const float* __restrict__ kk,
                                                float* __restrict__ qpart,
                                                float* __restrict__ kpart) {
  int lc = blockIdx.x, b = blockIdx.y;
  int c4 = threadIdx.x * 4;
  float aq0 = 0, aq1 = 0, aq2 = 0, aq3 = 0, ak0 = 0, ak1 = 0, ak2 = 0, ak3 = 0;
  const float* qp = q + ((size_t)b * LL + (size_t)lc * 64) * DD + c4;
  const float* kp = kk + ((size_t)b * LL + (size_t)lc * 64) * DD + c4;
#pragma unroll 4
  for (int l = 0; l < 64; ++l) {
    float4 x = *(const float4*)(qp + (size_t)l * DD);
    float4 y = *(const float4*)(kp + (size_t)l * DD);
    aq0 += x.x; aq1 += x.y; aq2 += x.z; aq3 += x.w;
    ak0 += y.x; ak1 += y.y; ak2 += y.z; ak3 += y.w;
  }
  float4 oq = {aq0, aq1, aq2, aq3};
  float4 ok = {ak0, ak1, ak2, ak3};
  *(float4*)&qpart[((size_t)b * 64 + lc) * DD + c4] = oq;
  *(float4*)&kpart[((size_t)b * 64 + lc) * DD + c4] = ok;
}

// ---------------- K1b: reduce partials -> sq, sk [B][D] ----------------
__global__ __launch_bounds__(128) void k_colsum2(const float* __restrict__ qpart,
                                                 const float* __restrict__ kpart,
                                                 float* __restrict__ sq,
                                                 float* __restrict__ sk) {
  int b = blockIdx.x;
  int c4 = threadIdx.x * 4;
  float aq0 = 0, aq1 = 0, aq2 = 0, aq3 = 0, ak0 = 0, ak1 = 0, ak2 = 0, ak3 = 0;
  for (int p = 0; p < 64; ++p) {
    float4 x = *(const float4*)&qpart[((size_t)b * 64 + p) * DD + c4];
    float4 y = *(const float4*)&kpart[((size_t)b * 64 + p) * DD + c4];
    aq0 += x.x; aq1 += x.y; aq2 += x.z; aq3 += x.w;
    ak0 += y.x; ak1 += y.y; ak2 += y.z; ak3 += y.w;
  }
  float4 oq = {aq0, aq1, aq2, aq3};
  float4 ok = {ak0, ak1, ak2, ak3};
  *(float4*)&sq[(size_t)b * DD + c4] = oq;
  *(float4*)&sk[(size_t)b * DD + c4] = ok;
}

// ------- K2a: parallel partial projections: sq@Wq, sk@Wk, bv@Wo -------
__global__ __launch_bounds__(256) void k_proj(
    const float* __restrict__ sq, const float* __restrict__ sk,
    const float* __restrict__ Wq, const float* __restrict__ Wk,
    const float* __restrict__ bv, const float* __restrict__ Wo,
    float* __restrict__ partQ, float* __restrict__ partK,
    float* __restrict__ partO) {
  int jc = blockIdx.x;     // 8 chunks of 64 rows of W
  int which = blockIdx.y;  // 0=q, 1=k, 2=o
  int tid = threadIdx.x;
  int j0 = jc * 64;
  if (which == 2) {
    float a0 = 0.f, a1 = 0.f;
    for (int j = 0; j < 64; ++j) {
      float b = bv[j0 + j];
      a0 += b * Wo[(size_t)(j0 + j) * DD + tid];
      a1 += b * Wo[(size_t)(j0 + j) * DD + tid + 256];
    }
    partO[(size_t)jc * DD + tid] = a0;
    partO[(size_t)jc * DD + tid + 256] = a1;
    return;
  }
  const float* s = (which == 0) ? sq : sk;
  const float* W = (which == 0) ? Wq : Wk;
  __shared__ float ss[BB][64];
  for (int t = tid; t < BB * 64; t += 256)
    ss[t >> 6][t & 63] = s[(size_t)(t >> 6) * DD + j0 + (t & 63)];
  __syncthreads();
  float a[BB][2];
#pragma unroll
  for (int b = 0; b < BB; ++b) { a[b][0] = 0.f; a[b][1] = 0.f; }
  for (int j = 0; j < 64; ++j) {
    float w0 = W[(size_t)(j0 + j) * DD + tid];
    float w1 = W[(size_t)(j0 + j) * DD + tid + 256];
#pragma unroll
    for (int b = 0; b < BB; ++b) {
      float sv = ss[b][j];
      a[b][0] += sv * w0;
      a[b][1] += sv * w1;
    }
  }
  float* part = (which == 0) ? partQ : partK;
#pragma unroll
  for (int b = 0; b < BB; ++b) {
    part[((size_t)jc * BB + b) * DD + tid] = a[b][0];
    part[((size_t)jc * BB + b) * DD + tid + 256] = a[b][1];
  }
}

// ------- K2b: reduce partials, mean_value, top-41, softmax, bvo -------
__global__ __launch_bounds__(512) void k_stats2(
    const float* __restrict__ partQ, const float* __restrict__ partK,
    const float* __restrict__ partO,
    const float* __restrict__ bq, const float* __restrict__ bk,
    const float* __restrict__ bo,
    int* __restrict__ idx_out, float* __restrict__ wts_out,
    float* __restrict__ bvo_out) {
  __shared__ float Sq[BB][DD];
  __shared__ float Sk[BB][DD];
  __shared__ float mvs[BB][64];
  __shared__ float mab[64];
  __shared__ int idxs[64];
  int tid = threadIdx.x;
  float bqv = bq[tid] * (float)LL, bkv = bk[tid] * (float)LL;
#pragma unroll
  for (int b = 0; b < BB; ++b) {
    float aq = 0.f, ak = 0.f;
#pragma unroll
    for (int jc = 0; jc < 8; ++jc) {
      aq += partQ[((size_t)jc * BB + b) * DD + tid];
      ak += partK[((size_t)jc * BB + b) * DD + tid];
    }
    Sq[b][tid] = aq + bqv;
    Sk[b][tid] = ak + bkv;
  }
  {
    float ao = 0.f;
#pragma unroll
    for (int jc = 0; jc < 8; ++jc) ao += partO[(size_t)jc * DD + tid];
    bvo_out[tid] = ao + bo[tid];
  }
  __syncthreads();
  {
    int b = tid >> 6, d = tid & 63;
    float s = 0.f;
#pragma unroll
    for (int h = 0; h < 8; ++h) s += Sq[b][h * 64 + d] * Sk[b][h * 64 + d];
    mvs[b][d] = s * (1.0f / ((float)LL * 8.0f));
  }
  __syncthreads();
  if (tid < 64) {
    float s = 0.f;
#pragma unroll
    for (int b = 0; b < BB; ++b) s += mvs[b][tid];
    mab[tid] = s * 0.125f;
  }
  __syncthreads();
  if (tid < 64) {
    float x = mab[tid];
    int r = 0;
    for (int d = 0; d < 64; ++d) {
      float y = mab[d];
      r += (y > x || (y == x && d < tid)) ? 1 : 0;
    }
    if (r < KSEL) { idxs[r] = tid; idx_out[r] = tid; }
  }
  __syncthreads();
  if (tid < BB) {
    int b = tid;
    float mx = -3.4e38f;
    for (int i = 0; i < KSEL; ++i) mx = fmaxf(mx, mvs[b][idxs[i]]);
    float s = 0.f;
    for (int i = 0; i < KSEL; ++i) s += expf(mvs[b][idxs[i]] - mx);
    float inv = 1.f / s;
    for (int i = 0; i < KSEL; ++i) wts_out[b * 64 + i] = expf(mvs[b][idxs[i]] - mx) * inv;
  }
}

// ------- K3: Wvo^T (bf16) = (Wv @ Wo)^T, fused -------
__global__ __launch_bounds__(256) void k_wvot(const float* __restrict__ Wv,
                                              const float* __restrict__ Wo,
                                              ushort* __restrict__ WT) {
  __shared__ float wv[8][512];  // 16 KB
  int tid = threadIdx.x;
  int c = blockIdx.x * 256 + tid;
  int j0 = blockIdx.y * 8;
  for (int t = tid; t < 8 * 512; t += 256)
    wv[t >> 9][t & 511] = Wv[(size_t)(j0 + (t >> 9)) * DD + (t & 511)];
  __syncthreads();
  float acc[8] = {0, 0, 0, 0, 0, 0, 0, 0};
  for (int m = 0; m < DD; ++m) {
    float wo = Wo[(size_t)m * DD + c];
#pragma unroll
    for (int j = 0; j < 8; ++j) acc[j] += wv[j][m] * wo;
  }
  ushort4 o0, o1;
  o0.x = f2bf(acc[0]); o0.y = f2bf(acc[1]); o0.z = f2bf(acc[2]); o0.w = f2bf(acc[3]);
  o1.x = f2bf(acc[4]); o1.y = f2bf(acc[5]); o1.z = f2bf(acc[6]); o1.w = f2bf(acc[7]);
  *(ushort4*)&WT[(size_t)c * DD + j0] = o0;
  *(ushort4*)&WT[(size_t)c * DD + j0 + 4] = o1;
}

// -------- K4: vagg = conv(v) via MFMA: tile[64 x 128ch] = M[64x128] @ vwin[128x128ch] --------
// M[r][j] = coef[j-r] (dense band from wts/idx). All delays in [0,64).
// LDS rows padded +16B (stride 272B) -> bank-spread without XOR swizzle.
__global__ __launch_bounds__(256) void k_conv(const float* __restrict__ v,
                                              const int* __restrict__ idx,
                                              const float* __restrict__ wts,
                                              ushort* __restrict__ vagg) {
  __shared__ ushort vwinT[128 * 136];  // [c][j], 272B stride  (34.8 KB)
  __shared__ ushort Mlds[64 * 136];    // [r][j], 272B stride  (17.4 KB)
  __shared__ float coefw[256];         // zero-padded coef, logical offset +64
  int lt = blockIdx.x;         // 64 l-tiles of 64 rows
  int ch0 = blockIdx.y * 128;  // 4 channel blocks
  int b = blockIdx.z;
  int tid = threadIdx.x;
  int l0 = lt * 64;

  coefw[tid] = 0.f;
  __syncthreads();
  if (tid < KSEL) coefw[64 + idx[tid]] = wts[b * 64 + tid];
  __syncthreads();

  // stage vwinT[c][j] = bf16(v[b][(l0+j)%L][ch0+c]): 8-row dword gather + b128 write
  {
    int c = tid & 127;
    int jh = tid >> 7;
    const float* vb = v + (size_t)b * LL * DD + ch0 + c;
#pragma unroll
    for (int it = 0; it < 8; ++it) {
      int j0 = (it * 2 + jh) * 8;
      union { unsigned int u[4]; short8 s; } pk;
#pragma unroll
      for (int p = 0; p < 4; ++p) {
        int ja = (l0 + j0 + 2 * p) & (LL - 1);
        int jb = (l0 + j0 + 2 * p + 1) & (LL - 1);
        float lo = vb[(size_t)ja * DD];
        float hi = vb[(size_t)jb * DD];
        pk.u[p] = (unsigned)f2bf(lo) | ((unsigned)f2bf(hi) << 16);
      }
      *(short8*)&vwinT[c * 136 + j0] = pk.s;
    }
  }
  // build M[r][j] = bf16(coefw[64 + j - r])  (zero outside band by padding)
#pragma unroll
  for (int it = 0; it < 8; ++it) {
    int e = (it * 256 + tid) * 4;
    int r = e >> 7, j0 = e & 127;
    ushort4 m4;
    m4.x = f2bf(coefw[64 + j0 + 0 - r]);
    m4.y = f2bf(coefw[64 + j0 + 1 - r]);
    m4.z = f2bf(coefw[64 + j0 + 2 - r]);
    m4.w = f2bf(coefw[64 + j0 + 3 - r]);
    *(ushort4*)&Mlds[r * 136 + j0] = m4;
  }
  __syncthreads();

  int lane = tid & 63, w = tid >> 6;
  int r15 = lane & 15, g = lane >> 4;
  f32x4 acc[4][2] = {};
#pragma unroll
  for (int ks = 0; ks < 4; ++ks) {
    int kc = ks * 4 + g;  // 16B k-chunk
    short8 av[4], bvv[2];
#pragma unroll
    for (int m = 0; m < 4; ++m)
      av[m] = *(const short8*)&Mlds[(m * 16 + r15) * 136 + kc * 8];
#pragma unroll
    for (int n = 0; n < 2; ++n)
      bvv[n] = *(const short8*)&vwinT[(w * 32 + n * 16 + r15) * 136 + kc * 8];
#pragma unroll
    for (int m = 0; m < 4; ++m)
#pragma unroll
      for (int n = 0; n < 2; ++n)
        acc[m][n] = __builtin_amdgcn_mfma_f32_16x16x32_bf16(av[m], bvv[n], acc[m][n], 0, 0, 0);
  }

  ushort* vout = vagg + ((size_t)b * LL + l0) * DD + ch0;
#pragma unroll
  for (int m = 0; m < 4; ++m)
#pragma unroll
    for (int n = 0; n < 2; ++n)
#pragma unroll
      for (int r = 0; r < 4; ++r) {
        int row = m * 16 + g * 4 + r;
        int col = w * 32 + n * 16 + r15;
        vout[(size_t)row * DD + col] = f2bf(acc[m][n][r]);
      }
}

// -------- K5: out = vagg(bf16) @ Wvo(bf16, stored transposed) + bvo  (f32) --------
__global__ __launch_bounds__(256) void k_gemm(const ushort* __restrict__ A,
                                              const ushort* __restrict__ BT,
                                              const float* __restrict__ bias,
                                              float* __restrict__ C) {
  __shared__ ushort lA[128 * 64];
  __shared__ ushort lB[128 * 64];
  int bcol = blockIdx.x * 128;
  int brow = blockIdx.y * 128;
  int tid = threadIdx.x;
  int lane = tid & 63, wid = tid >> 6;
  int wr = wid >> 1, wc = wid & 1;
  int r15 = lane & 15, g = lane >> 4;
  f32x4 acc[4][4] = {};
  for (int k0 = 0; k0 < DD; k0 += 64) {
#pragma unroll
    for (int it = 0; it < 4; ++it) {
      int ch = it * 256 + tid;  // lane-consecutive 16B chunks
      int row = ch >> 3;
      int clg = (ch & 7) ^ (row & 7);  // inverse-swizzled global source
      g2lds16(A + (size_t)(brow + row) * DD + k0 + clg * 8, &lA[ch * 8]);
      g2lds16(BT + (size_t)(bcol + row) * DD + k0 + clg * 8, &lB[ch * 8]);
    }
    asm volatile("s_waitcnt vmcnt(0)" ::: "memory");
    __syncthreads();
#pragma unroll
    for (int ks = 0; ks < 2; ++ks) {
      int kc = ks * 4 + g;  // logical 16B k-chunk for this lane group
      short8 av[4], bv[4];
#pragma unroll
      for (int m = 0; m < 4; ++m) {
        int row = wr * 64 + m * 16 + r15;
        av[m] = *(const short8*)&lA[(row * 8 + (kc ^ (row & 7))) * 8];
        int col = wc * 64 + m * 16 + r15;
        bv[m] = *(const short8*)&lB[(col * 8 + (kc ^ (col & 7))) * 8];
      }
#pragma unroll
      for (int m = 0; m < 4; ++m)
#pragma unroll
        for (int n = 0; n < 4; ++n)
          acc[m][n] = __builtin_amdgcn_mfma_f32_16x16x32_bf16(av[m], bv[n], acc[m][n], 0, 0, 0);
    }
    __syncthreads();
  }
#pragma unroll
  for (int n = 0; n < 4; ++n) {
    int col = bcol + wc * 64 + n * 16 + r15;
    float bc = bias[col];
#pragma unroll
    for (int m = 0; m < 4; ++m) {
      int row = brow + wr * 64 + m * 16 + g * 4;
#pragma unroll
      for (int r = 0; r < 4; ++r)
        C[(size_t)(row + r) * DD + col] = acc[m][n][r] + bc;
    }
  }
}

extern "C" void kernel_launch(void* const* d_in, const int* in_sizes, int n_in,
                              void* d_out, int out_size, void* d_ws, size_t ws_size,
                              hipStream_t stream) {
  const float* q  = (const float*)d_in[0];
  const float* k  = (const float*)d_in[1];
  const float* v  = (const float*)d_in[2];
  const float* Wq = (const float*)d_in[3];
  const float* bq = (const float*)d_in[4];
  const float* Wk = (const float*)d_in[5];
  const float* bk = (const float*)d_in[6];
  const float* Wv = (const float*)d_in[7];
  const float* bv = (const float*)d_in[8];
  const float* Wo = (const float*)d_in[9];
  const float* bo = (const float*)d_in[10];
  float* out = (float*)d_out;

  char* ws = (char*)d_ws;
  ushort* vagg  = (ushort*)(ws + 0x0);        // 32 MB bf16 [B*L*D]
  ushort* wvot  = (ushort*)(ws + 0x2100000);  // 512 KB bf16 [D][D] transposed
  float* qpart  = (float*)(ws + 0x2180000);   // 1 MB (dead after k_colsum2)
  float* kpart  = (float*)(ws + 0x2280000);   // 1 MB (dead after k_colsum2)
  float* sq     = (float*)(ws + 0x2380000);   // 16 KB
  float* sk     = (float*)(ws + 0x2384000);   // 16 KB
  int*   idx    = (int*)(ws + 0x2388800);     // 256 B
  float* wts    = (float*)(ws + 0x2388900);   // 2 KB
  float* bvo    = (float*)(ws + 0x2389100);   // 2 KB
  float* partQ  = (float*)(ws + 0x2180000);   // 128 KB (overlays dead qpart)
  float* partK  = (float*)(ws + 0x21A0000);   // 128 KB
  float* partO  = (float*)(ws + 0x21C0000);   // 16 KB

  k_colsum<<<dim3(64, 8), 128, 0, stream>>>(q, k, qpart, kpart);
  k_colsum2<<<dim3(8), 128, 0, stream>>>(qpart, kpart, sq, sk);
  k_proj<<<dim3(8, 3), 256, 0, stream>>>(sq, sk, Wq, Wk, bv, Wo, partQ, partK, partO);
  k_stats2<<<dim3(1), 512, 0, stream>>>(partQ, partK, partO, bq, bk, bo, idx, wts, bvo);
  k_wvot<<<dim3(2, 64), 256, 0, stream>>>(Wv, Wo, wvot);
  k_conv<<<dim3(64, 4, 8), 256, 0, stream>>>(v, idx, wts, vagg);
  k_gemm<<<dim3(4, 256), 256, 0, stream>>>(vagg, wvot, bvo, out);
}